// Round 4
// baseline (80.961 us; speedup 1.0000x reference)
//
#include <hip/hip_runtime.h>

#define SEQ 512
#define MD  1024
#define RK  128

typedef __attribute__((ext_vector_type(8))) short  bf16x8;
typedef __attribute__((ext_vector_type(4))) float  floatx4;
typedef __attribute__((ext_vector_type(4))) unsigned int uint4v;
typedef __attribute__((ext_vector_type(4))) unsigned short ushortx4;

__device__ inline unsigned short f2bf(float f) {
    union { float f; unsigned u; } v; v.f = f;
    unsigned r = v.u + 0x7fffu + ((v.u >> 16) & 1u);   // RNE, inputs are normal
    return (unsigned short)(r >> 16);
}

// ---------- Kernel 0: prep ----------
// blocks 0..31  : Pt[n][k] = bf16(proj[k][n])          (128 x 1024 bf16)
// blocks 32..287: Bb = bf16(batch), row-major           (4096 x 1024 bf16)
__global__ __launch_bounds__(256) void prep(
    const float* __restrict__ proj, const float* __restrict__ batch,
    unsigned short* __restrict__ Pt, unsigned short* __restrict__ Bb)
{
    const int t = threadIdx.x;
    if (blockIdx.x < 32) {
        __shared__ float Ls[64 * 68];    // 64 k x 64 n, pad 68
        const int k0 = ((int)blockIdx.x >> 1) * 64;
        const int n0 = ((int)blockIdx.x & 1) * 64;
        {   // coalesced read of 64x64 fp32 tile
            int kr = t >> 2;
            int nc = (t & 3) * 16;
            #pragma unroll
            for (int c = 0; c < 4; ++c) {
                float4 v = *(const float4*)(proj + (size_t)(k0 + kr) * RK + n0 + nc + c * 4);
                *(float4*)(Ls + kr * 68 + nc + c * 4) = v;
            }
        }
        __syncthreads();
        {   // transposed write: thread -> row n, 16 k's
            int nl = t >> 2;
            int kh = (t & 3) * 16;
            unsigned short tmp[16];
            #pragma unroll
            for (int kk = 0; kk < 16; ++kk)
                tmp[kk] = f2bf(Ls[(kh + kk) * 68 + nl]);
            *(uint4v*)(Pt + (size_t)(n0 + nl) * MD + k0 + kh)     = *(uint4v*)(tmp);
            *(uint4v*)(Pt + (size_t)(n0 + nl) * MD + k0 + kh + 8) = *(uint4v*)(tmp + 8);
        }
    } else {
        // convert one 16-row strip of batch (16384 floats), fully coalesced
        const int bb = (int)blockIdx.x - 32;
        const float* src = batch + (size_t)bb * 16 * MD;
        unsigned short* dst = Bb + (size_t)bb * 16 * MD;
        #pragma unroll
        for (int c = 0; c < 8; ++c) {
            int i = (c * 256 + t) * 8;
            float4 a = *(const float4*)(src + i);
            float4 b = *(const float4*)(src + i + 4);
            unsigned short tmp[8];
            tmp[0] = f2bf(a.x); tmp[1] = f2bf(a.y); tmp[2] = f2bf(a.z); tmp[3] = f2bf(a.w);
            tmp[4] = f2bf(b.x); tmp[5] = f2bf(b.y); tmp[6] = f2bf(b.z); tmp[7] = f2bf(b.w);
            *(uint4v*)(dst + i) = *(uint4v*)tmp;
        }
    }
}

// ---------- Kernel 1: T = bf16( Bb @ Pt^T ) + row norms, via MFMA ----------
// 256 blocks x 512 threads (8 waves). Block owns 16 rows; wave w owns a K-eighth.
// A and B frags are direct bf16 dwordx4 loads. One barrier before the reduce.
#define REDW 2112   // 16 * 132 floats per wave partial

__global__ __launch_bounds__(512, 2) void proj_mfma(
    const unsigned short* __restrict__ Bb, const unsigned short* __restrict__ Pt,
    unsigned short* __restrict__ T, float* __restrict__ Nrm)
{
    __shared__ float Red[8 * REDW];   // 67.6 KB

    const int t    = threadIdx.x;
    const int w    = t >> 6;
    const int l    = t & 63;
    const int lm   = l & 15;
    const int quad = l >> 4;
    const int r0   = blockIdx.x * 16;

    floatx4 acc[8];
    #pragma unroll
    for (int i = 0; i < 8; ++i) acc[i] = (floatx4){0.f, 0.f, 0.f, 0.f};

    const unsigned short* arow = Bb + (size_t)(r0 + lm) * MD + w * 128 + quad * 8;
    const unsigned short* brow = Pt + (size_t)lm * MD + w * 128 + quad * 8;

    #pragma unroll
    for (int s = 0; s < 4; ++s) {
        bf16x8 av = *(const bf16x8*)(arow + s * 32);
        #pragma unroll
        for (int nt = 0; nt < 8; ++nt) {
            bf16x8 bv = *(const bf16x8*)(brow + (size_t)nt * 16 * MD + s * 32);
            acc[nt] = __builtin_amdgcn_mfma_f32_16x16x32_bf16(av, bv, acc[nt], 0, 0, 0);
        }
    }

    // dump per-wave partials; row stride 132 -> 2-way bank alias only (free)
    #pragma unroll
    for (int nt = 0; nt < 8; ++nt) {
        #pragma unroll
        for (int r = 0; r < 4; ++r) {
            Red[w * REDW + (quad * 4 + r) * 132 + nt * 16 + lm] = acc[nt][r];
        }
    }
    __syncthreads();

    // conflict-free b128 reduce: thread -> (row = t>>5, col4 = (t&31)*4)
    {
        const int row  = t >> 5;
        const int col4 = (t & 31) * 4;
        float4 s4 = {0.f, 0.f, 0.f, 0.f};
        #pragma unroll
        for (int ww = 0; ww < 8; ++ww) {
            float4 p = *(const float4*)(Red + ww * REDW + row * 132 + col4);
            s4.x += p.x; s4.y += p.y; s4.z += p.z; s4.w += p.w;
        }
        unsigned short tmp[4];
        tmp[0] = f2bf(s4.x); tmp[1] = f2bf(s4.y);
        tmp[2] = f2bf(s4.z); tmp[3] = f2bf(s4.w);
        *(ushortx4*)(T + (size_t)(r0 + row) * RK + col4) = *(ushortx4*)tmp;

        // fused row norm: reduce ||T_row||^2 across the 32 lanes owning the row
        float ss = s4.x * s4.x + s4.y * s4.y + s4.z * s4.z + s4.w * s4.w;
        ss += __shfl_xor(ss, 1,  64);
        ss += __shfl_xor(ss, 2,  64);
        ss += __shfl_xor(ss, 4,  64);
        ss += __shfl_xor(ss, 8,  64);
        ss += __shfl_xor(ss, 16, 64);
        if ((t & 31) == 0) Nrm[r0 + row] = ss;
    }
}

// ---------- Kernel 2: D[b,i,j] = nI + nJ - 2 * (T_i . T_j), via MFMA ----------
// Grid (8 jt, 8 it, 8 b), 256 threads = 4 waves; 64x64 tile; wave w -> 16 i-rows.
#define LDB 136   // 128 + 8 bf16 pad: 16B rows, stride/16B odd -> 2-way alias only

__global__ __launch_bounds__(256) void dist_mfma(
    const unsigned short* __restrict__ T, const float* __restrict__ Nrm,
    float* __restrict__ out)
{
    __shared__ unsigned short Ti[64 * LDB];
    __shared__ unsigned short Tj[64 * LDB];
    __shared__ float nI[64], nJ[64];

    const int t    = threadIdx.x;
    const int w    = t >> 6;
    const int l    = t & 63;
    const int lm   = l & 15;
    const int quad = l >> 4;
    const int jt = blockIdx.x, it = blockIdx.y, b = blockIdx.z;
    const int i0 = it * 64, j0 = jt * 64;
    const unsigned short* Tb = T + (size_t)b * SEQ * RK;

    {   // stage both 64x128 bf16 tiles + norms
        int row = t >> 2, kq = (t & 3) * 32;
        const unsigned short* si = Tb + (size_t)(i0 + row) * RK + kq;
        const unsigned short* sj = Tb + (size_t)(j0 + row) * RK + kq;
        #pragma unroll
        for (int q = 0; q < 4; ++q) {
            *(uint4v*)(Ti + row * LDB + kq + q * 8) = *(const uint4v*)(si + q * 8);
            *(uint4v*)(Tj + row * LDB + kq + q * 8) = *(const uint4v*)(sj + q * 8);
        }
        if (t < 64)       nI[t]      = Nrm[(size_t)b * SEQ + i0 + t];
        else if (t < 128) nJ[t - 64] = Nrm[(size_t)b * SEQ + j0 + (t - 64)];
    }
    __syncthreads();

    floatx4 acc[4];
    #pragma unroll
    for (int i = 0; i < 4; ++i) acc[i] = (floatx4){0.f, 0.f, 0.f, 0.f};

    #pragma unroll
    for (int s = 0; s < 4; ++s) {
        bf16x8 av = *(const bf16x8*)(Ti + (w * 16 + lm) * LDB + s * 32 + quad * 8);
        #pragma unroll
        for (int nt = 0; nt < 4; ++nt) {
            bf16x8 bv = *(const bf16x8*)(Tj + (nt * 16 + lm) * LDB + s * 32 + quad * 8);
            acc[nt] = __builtin_amdgcn_mfma_f32_16x16x32_bf16(av, bv, acc[nt], 0, 0, 0);
        }
    }

    float niv[4];
    #pragma unroll
    for (int r = 0; r < 4; ++r) niv[r] = nI[w * 16 + quad * 4 + r];

    float* ob = out + ((size_t)b * SEQ + (i0 + w * 16)) * SEQ + j0;
    #pragma unroll
    for (int nt = 0; nt < 4; ++nt) {
        float njv = nJ[nt * 16 + lm];
        #pragma unroll
        for (int r = 0; r < 4; ++r) {
            ob[(size_t)(quad * 4 + r) * SEQ + nt * 16 + lm] =
                niv[r] + njv - 2.f * acc[nt][r];
        }
    }
}

extern "C" void kernel_launch(void* const* d_in, const int* in_sizes, int n_in,
                              void* d_out, int out_size, void* d_ws, size_t ws_size,
                              hipStream_t stream) {
    const float* batch = (const float*)d_in[0];   // (8, 512, 1024) fp32
    const float* proj  = (const float*)d_in[1];   // (1024, 128) fp32
    float* out = (float*)d_out;                   // (8, 512, 512) fp32

    unsigned short* T   = (unsigned short*)d_ws;                          // 1 MB bf16
    unsigned short* Pt  = (unsigned short*)((char*)d_ws + (1 << 20));     // 256 KB bf16
    float*          Nrm = (float*)((char*)d_ws + (1 << 20) + (1 << 18));  // 16 KB fp32
    unsigned short* Bb  = (unsigned short*)((char*)d_ws + (1 << 20) + (1 << 19)); // 8 MB bf16

    prep<<<288, 256, 0, stream>>>(proj, batch, Pt, Bb);
    proj_mfma<<<256, 512, 0, stream>>>(Bb, Pt, T, Nrm);
    dist_mfma<<<dim3(8, 8, 8), 256, 0, stream>>>(T, Nrm, out);
}